// Round 11
// baseline (26.942 us; speedup 1.0000x reference)
//
#include <hip/hip_runtime.h>
#include <hip/hip_bf16.h>
#include <math.h>

#define NBINS   1024
#define NPART   512     // hist grid: 512 blocks x 2 batches x 128 rows
#define NCHUNK  32
#define PPC     16      // partials per chunk in reduce (NPART/NCHUNK)
#define LSTRIDE 72      // ushorts per bin-row: 144B, 16B-aligned slots

typedef __attribute__((ext_vector_type(8)))  short short8;   // 8 bf16 = 4 VGPR
typedef __attribute__((ext_vector_type(16))) float f32x16;   // MFMA 32x32 acc

// ws layout: gC[NPART*NBINS] partials (2MB) | g2[32*1024] (128KB) | counter (i32).
// 2 kernels: hist (R10-verified) + fused reduce/finalize (last-block pattern,
// 128-block stage-1 geometry preserved from the verified R10 reduce).

__device__ __forceinline__ void make_trees(const float v[10], float valid,
                                           float hi[32], float lo[32])
{
    {
        float t2[2], t4[4], t8[8], t16[16];
        t2[0] = valid * (1.0f - v[0]); t2[1] = valid * v[0];
        #pragma unroll
        for (int k = 0; k < 4; ++k)  t4[k]  = t2[k >> 1]  * ((k & 1) ? v[1] : 1.0f - v[1]);
        #pragma unroll
        for (int k = 0; k < 8; ++k)  t8[k]  = t4[k >> 1]  * ((k & 1) ? v[2] : 1.0f - v[2]);
        #pragma unroll
        for (int k = 0; k < 16; ++k) t16[k] = t8[k >> 1]  * ((k & 1) ? v[3] : 1.0f - v[3]);
        #pragma unroll
        for (int k = 0; k < 32; ++k) hi[k]  = t16[k >> 1] * ((k & 1) ? v[4] : 1.0f - v[4]);
    }
    {
        float t2[2], t4[4], t8[8], t16[16];
        t2[0] = 1.0f - v[5]; t2[1] = v[5];
        #pragma unroll
        for (int k = 0; k < 4; ++k)  t4[k]  = t2[k >> 1]  * ((k & 1) ? v[6] : 1.0f - v[6]);
        #pragma unroll
        for (int k = 0; k < 8; ++k)  t8[k]  = t4[k >> 1]  * ((k & 1) ? v[7] : 1.0f - v[7]);
        #pragma unroll
        for (int k = 0; k < 16; ++k) t16[k] = t8[k >> 1]  * ((k & 1) ? v[8] : 1.0f - v[8]);
        #pragma unroll
        for (int k = 0; k < 32; ++k) lo[k]  = t16[k >> 1] * ((k & 1) ? v[9] : 1.0f - v[9]);
    }
}

__global__ __launch_bounds__(128, 2) void hist_kernel(const float* __restrict__ act,
                                                      float* __restrict__ gC,
                                                      int* __restrict__ counter,
                                                      int rows)
{
    __shared__ ushort Phi_u[2][32][LSTRIDE];   // 9KB
    __shared__ ushort Plo_u[2][32][LSTRIDE];   // 9KB
    __shared__ float  C_lds[NBINS];            // 4KB

    const int tid  = threadIdx.x;
    const int wav  = tid >> 6;
    const int lane = tid & 63;

    if (blockIdx.x == 0 && tid == 0) *counter = 0;   // for kernel 2 (boundary orders)

    const int r0 = blockIdx.x * 256 + tid;     // batch 0 row
    const int r1 = r0 + 128;                   // batch 1 row

    float v0[10], v1[10];
    float valid0 = 1.0f, valid1 = 1.0f;
    if (r0 < rows) {
        const float2* a2 = (const float2*)(act + (size_t)r0 * 10);
        #pragma unroll
        for (int k = 0; k < 5; ++k) { float2 t = a2[k]; v0[2*k] = t.x; v0[2*k+1] = t.y; }
    } else {
        valid0 = 0.0f;
        #pragma unroll
        for (int k = 0; k < 10; ++k) v0[k] = 0.0f;
    }
    if (r1 < rows) {
        const float2* a2 = (const float2*)(act + (size_t)r1 * 10);
        #pragma unroll
        for (int k = 0; k < 5; ++k) { float2 t = a2[k]; v1[2*k] = t.x; v1[2*k+1] = t.y; }
    } else {
        valid1 = 0.0f;
        #pragma unroll
        for (int k = 0; k < 10; ++k) v1[k] = 0.0f;
    }

    const int m  = lane & 31;
    const int kh = (lane >> 5) * 8;      // 0 or 8
    f32x16 acc = {};

    // ---- batch 0 ----
    {
        float hi[32], lo[32];
        make_trees(v0, valid0, hi, lo);
        #pragma unroll
        for (int q = 0; q < 32; ++q) {
            __hip_bfloat16 bh = __float2bfloat16(hi[q]);
            __hip_bfloat16 bl = __float2bfloat16(lo[q]);
            Phi_u[wav][q][lane] = *(const ushort*)&bh;
            Plo_u[wav][q][lane] = *(const ushort*)&bl;
        }
        __syncthreads();
        #pragma unroll
        for (int t = 0; t < 4; ++t) {
            const short8 a = *(const short8*)&Phi_u[wav][m][kh + 16 * t];
            const short8 b = *(const short8*)&Plo_u[wav][m][kh + 16 * t];
            acc = __builtin_amdgcn_mfma_f32_32x32x16_bf16(a, b, acc, 0, 0, 0);
        }
        __syncthreads();
    }
    // ---- batch 1 ----
    {
        float hi[32], lo[32];
        make_trees(v1, valid1, hi, lo);
        #pragma unroll
        for (int q = 0; q < 32; ++q) {
            __hip_bfloat16 bh = __float2bfloat16(hi[q]);
            __hip_bfloat16 bl = __float2bfloat16(lo[q]);
            Phi_u[wav][q][lane] = *(const ushort*)&bh;
            Plo_u[wav][q][lane] = *(const ushort*)&bl;
        }
        __syncthreads();
        #pragma unroll
        for (int t = 0; t < 4; ++t) {
            const short8 a = *(const short8*)&Phi_u[wav][m][kh + 16 * t];
            const short8 b = *(const short8*)&Plo_u[wav][m][kh + 16 * t];
            acc = __builtin_amdgcn_mfma_f32_32x32x16_bf16(a, b, acc, 0, 0, 0);
        }
    }

    // Merge 2 waves without atomics: wave1 stores, wave0 adds. 2/bank = free.
    if (wav == 1) {
        #pragma unroll
        for (int r = 0; r < 16; ++r)
            C_lds[r * 64 + lane] = acc[r];
    }
    __syncthreads();
    if (wav == 0) {
        #pragma unroll
        for (int r = 0; r < 16; ++r)
            C_lds[r * 64 + lane] += acc[r];
    }
    __syncthreads();

    float4* dst4 = (float4*)(gC + (size_t)blockIdx.x * NBINS);
    const float4* src4 = (const float4*)C_lds;
    dst4[tid]       = src4[tid];
    dst4[tid + 128] = src4[tid + 128];
}

// Fused reduce + finalize. 128 blocks x 256 threads (R10-verified stage-1
// geometry); the last block to finish runs the entropy finalize.
__global__ __launch_bounds__(256) void reduce_kernel(const float* __restrict__ gC,
                                                     float* __restrict__ g2,
                                                     int* __restrict__ counter,
                                                     float* __restrict__ out,
                                                     float invB)
{
    __shared__ int amlast;
    __shared__ float red[4];
    const int tid = threadIdx.x;

    // stage 1: identical work/order to R10's reduce_kernel
    {
        const int chunk = blockIdx.x >> 2;                    // 0..31
        const int bin   = (blockIdx.x & 3) * 256 + tid;
        const float* p  = gC + (size_t)chunk * PPC * NBINS + bin;
        float s = 0.0f;
        #pragma unroll
        for (int k = 0; k < PPC; ++k) s += p[k * NBINS];      // coalesced
        g2[chunk * NBINS + bin] = s;
    }

    __threadfence();          // release: g2 store visible device-wide
    __syncthreads();          // all lanes' stores+fences precede the counter bump
    if (tid == 0) {
        const int old = __hip_atomic_fetch_add(counter, 1, __ATOMIC_ACQ_REL,
                                               __HIP_MEMORY_SCOPE_AGENT);
        amlast = (old == 127);
    }
    __syncthreads();
    if (!amlast) return;
    __threadfence();          // acquire: all 128 blocks' g2 stores visible

    // stage 2 (= R10 finalize, same summation order -> identical result)
    float4 acc = make_float4(0.f, 0.f, 0.f, 0.f);
    #pragma unroll
    for (int s = 0; s < NCHUNK; ++s) {
        const float4 t = *(const float4*)&g2[s * NBINS + tid * 4];
        acc.x += t.x; acc.y += t.y; acc.z += t.z; acc.w += t.w;
    }

    float s = 0.0f;
    const float b[4] = {acc.x, acc.y, acc.z, acc.w};
    #pragma unroll
    for (int k = 0; k < 4; ++k) {
        const float p  = b[k] * invB;
        const float ps = fmaxf(p, 1e-12f);
        s += p * log2f(ps);   // out = sum p*log2(clip(p)) = -joint_h
    }
    #pragma unroll
    for (int off = 32; off > 0; off >>= 1) s += __shfl_down(s, off);
    if ((tid & 63) == 0) red[tid >> 6] = s;
    __syncthreads();
    if (tid == 0) out[0] = red[0] + red[1] + red[2] + red[3];
}

extern "C" void kernel_launch(void* const* d_in, const int* in_sizes, int n_in,
                              void* d_out, int out_size, void* d_ws, size_t ws_size,
                              hipStream_t stream)
{
    const float* act = (const float*)d_in[0];
    const int rows = in_sizes[0] / 10;        // B = 131072 = 512 * 256
    float* gC      = (float*)d_ws;            // NPART x NBINS partials (2MB)
    float* g2      = gC + (size_t)NPART * NBINS;   // 32 x 1024 (128KB)
    int*   counter = (int*)(g2 + NCHUNK * NBINS);

    hist_kernel<<<NPART, 128, 0, stream>>>(act, gC, counter, rows);
    reduce_kernel<<<128, 256, 0, stream>>>(gC, g2, counter, (float*)d_out,
                                           1.0f / (float)rows);
}

// Round 12
// 14.424 us; speedup vs baseline: 1.8679x; 1.8679x over previous
//
#include <hip/hip_runtime.h>
#include <hip/hip_bf16.h>
#include <math.h>

#define NBINS   1024
#define NPART   512     // hist grid: 512 blocks x 2 batches x 128 rows
#define LSTRIDE 72      // ushorts per bin-row: 144B, 16B-aligned slots

typedef __attribute__((ext_vector_type(8)))  short short8;   // 8 bf16 = 4 VGPR
typedef __attribute__((ext_vector_type(16))) float f32x16;   // MFMA 32x32 acc

// ws layout: gC[NPART*NBINS] partials (2MB). 2 kernels, no fences/counters:
// hist (R10-verified, + block0 zeroes out[0]) -> bins-complete-per-block
// reduce+finalize (128 blocks, 4-accumulator MLP reads, 1 atomicAdd/block).

__device__ __forceinline__ void make_trees(const float v[10], float valid,
                                           float hi[32], float lo[32])
{
    {
        float t2[2], t4[4], t8[8], t16[16];
        t2[0] = valid * (1.0f - v[0]); t2[1] = valid * v[0];
        #pragma unroll
        for (int k = 0; k < 4; ++k)  t4[k]  = t2[k >> 1]  * ((k & 1) ? v[1] : 1.0f - v[1]);
        #pragma unroll
        for (int k = 0; k < 8; ++k)  t8[k]  = t4[k >> 1]  * ((k & 1) ? v[2] : 1.0f - v[2]);
        #pragma unroll
        for (int k = 0; k < 16; ++k) t16[k] = t8[k >> 1]  * ((k & 1) ? v[3] : 1.0f - v[3]);
        #pragma unroll
        for (int k = 0; k < 32; ++k) hi[k]  = t16[k >> 1] * ((k & 1) ? v[4] : 1.0f - v[4]);
    }
    {
        float t2[2], t4[4], t8[8], t16[16];
        t2[0] = 1.0f - v[5]; t2[1] = v[5];
        #pragma unroll
        for (int k = 0; k < 4; ++k)  t4[k]  = t2[k >> 1]  * ((k & 1) ? v[6] : 1.0f - v[6]);
        #pragma unroll
        for (int k = 0; k < 8; ++k)  t8[k]  = t4[k >> 1]  * ((k & 1) ? v[7] : 1.0f - v[7]);
        #pragma unroll
        for (int k = 0; k < 16; ++k) t16[k] = t8[k >> 1]  * ((k & 1) ? v[8] : 1.0f - v[8]);
        #pragma unroll
        for (int k = 0; k < 32; ++k) lo[k]  = t16[k >> 1] * ((k & 1) ? v[9] : 1.0f - v[9]);
    }
}

__global__ __launch_bounds__(128, 2) void hist_kernel(const float* __restrict__ act,
                                                      float* __restrict__ gC,
                                                      float* __restrict__ out,
                                                      int rows)
{
    __shared__ ushort Phi_u[2][32][LSTRIDE];   // 9KB
    __shared__ ushort Plo_u[2][32][LSTRIDE];   // 9KB
    __shared__ float  C_lds[NBINS];            // 4KB

    const int tid  = threadIdx.x;
    const int wav  = tid >> 6;
    const int lane = tid & 63;

    // re-init out each call; kernel boundary orders this before reduce's atomics
    if (blockIdx.x == 0 && tid == 0) out[0] = 0.0f;

    const int r0 = blockIdx.x * 256 + tid;     // batch 0 row
    const int r1 = r0 + 128;                   // batch 1 row

    float v0[10], v1[10];
    float valid0 = 1.0f, valid1 = 1.0f;
    if (r0 < rows) {
        const float2* a2 = (const float2*)(act + (size_t)r0 * 10);
        #pragma unroll
        for (int k = 0; k < 5; ++k) { float2 t = a2[k]; v0[2*k] = t.x; v0[2*k+1] = t.y; }
    } else {
        valid0 = 0.0f;
        #pragma unroll
        for (int k = 0; k < 10; ++k) v0[k] = 0.0f;
    }
    if (r1 < rows) {
        const float2* a2 = (const float2*)(act + (size_t)r1 * 10);
        #pragma unroll
        for (int k = 0; k < 5; ++k) { float2 t = a2[k]; v1[2*k] = t.x; v1[2*k+1] = t.y; }
    } else {
        valid1 = 0.0f;
        #pragma unroll
        for (int k = 0; k < 10; ++k) v1[k] = 0.0f;
    }

    const int m  = lane & 31;
    const int kh = (lane >> 5) * 8;      // 0 or 8
    f32x16 acc = {};

    // ---- batch 0 ----
    {
        float hi[32], lo[32];
        make_trees(v0, valid0, hi, lo);
        #pragma unroll
        for (int q = 0; q < 32; ++q) {
            __hip_bfloat16 bh = __float2bfloat16(hi[q]);
            __hip_bfloat16 bl = __float2bfloat16(lo[q]);
            Phi_u[wav][q][lane] = *(const ushort*)&bh;
            Plo_u[wav][q][lane] = *(const ushort*)&bl;
        }
        __syncthreads();
        #pragma unroll
        for (int t = 0; t < 4; ++t) {
            const short8 a = *(const short8*)&Phi_u[wav][m][kh + 16 * t];
            const short8 b = *(const short8*)&Plo_u[wav][m][kh + 16 * t];
            acc = __builtin_amdgcn_mfma_f32_32x32x16_bf16(a, b, acc, 0, 0, 0);
        }
        __syncthreads();
    }
    // ---- batch 1 ----
    {
        float hi[32], lo[32];
        make_trees(v1, valid1, hi, lo);
        #pragma unroll
        for (int q = 0; q < 32; ++q) {
            __hip_bfloat16 bh = __float2bfloat16(hi[q]);
            __hip_bfloat16 bl = __float2bfloat16(lo[q]);
            Phi_u[wav][q][lane] = *(const ushort*)&bh;
            Plo_u[wav][q][lane] = *(const ushort*)&bl;
        }
        __syncthreads();
        #pragma unroll
        for (int t = 0; t < 4; ++t) {
            const short8 a = *(const short8*)&Phi_u[wav][m][kh + 16 * t];
            const short8 b = *(const short8*)&Plo_u[wav][m][kh + 16 * t];
            acc = __builtin_amdgcn_mfma_f32_32x32x16_bf16(a, b, acc, 0, 0, 0);
        }
    }

    // Merge 2 waves without atomics: wave1 stores, wave0 adds. 2/bank = free.
    if (wav == 1) {
        #pragma unroll
        for (int r = 0; r < 16; ++r)
            C_lds[r * 64 + lane] = acc[r];
    }
    __syncthreads();
    if (wav == 0) {
        #pragma unroll
        for (int r = 0; r < 16; ++r)
            C_lds[r * 64 + lane] += acc[r];
    }
    __syncthreads();

    float4* dst4 = (float4*)(gC + (size_t)blockIdx.x * NBINS);
    const float4* src4 = (const float4*)C_lds;
    dst4[tid]       = src4[tid];
    dst4[tid + 128] = src4[tid + 128];
}

// Fused reduce + finalize, bins-complete-per-block. 128 blocks x 256 threads;
// block bx owns bins bx*8..bx*8+7. Thread (g,b) sums partials g+32j (j=0..15)
// with 4 independent accumulators (anti-R9: 16 loads in flight, no serial chain).
__global__ __launch_bounds__(256) void reduce_kernel(const float* __restrict__ gC,
                                                     float* __restrict__ out,
                                                     float invB)
{
    __shared__ float red[32][8];     // [partial-group][bin-local]
    const int tid = threadIdx.x;
    const int g   = tid >> 3;        // 0..31
    const int b   = tid & 7;         // 0..7
    const int bin = blockIdx.x * 8 + b;

    const float* p = gC + (size_t)g * NBINS + bin;   // +32*NBINS per step
    float a0 = 0.f, a1 = 0.f, a2 = 0.f, a3 = 0.f;
    #pragma unroll
    for (int j = 0; j < 16; j += 4) {
        a0 += p[(size_t)(j + 0) * 32 * NBINS];
        a1 += p[(size_t)(j + 1) * 32 * NBINS];
        a2 += p[(size_t)(j + 2) * 32 * NBINS];
        a3 += p[(size_t)(j + 3) * 32 * NBINS];
    }
    red[g][b] = (a0 + a1) + (a2 + a3);
    __syncthreads();

    if (tid < 8) {
        float t = 0.0f;
        #pragma unroll
        for (int k = 0; k < 32; ++k) t += red[k][tid];
        const float pa = t * invB;
        float e = pa * log2f(fmaxf(pa, 1e-12f));   // sum p*log2(clip(p)) = -joint_h
        e += __shfl_down(e, 4);
        e += __shfl_down(e, 2);
        e += __shfl_down(e, 1);
        if (tid == 0) atomicAdd(out, e);           // 128 adds total, device scope
    }
}

extern "C" void kernel_launch(void* const* d_in, const int* in_sizes, int n_in,
                              void* d_out, int out_size, void* d_ws, size_t ws_size,
                              hipStream_t stream)
{
    const float* act = (const float*)d_in[0];
    const int rows = in_sizes[0] / 10;        // B = 131072 = 512 * 256
    float* gC  = (float*)d_ws;                // NPART x NBINS partials (2MB)
    float* out = (float*)d_out;

    hist_kernel<<<NPART, 128, 0, stream>>>(act, gC, out, rows);
    reduce_kernel<<<128, 256, 0, stream>>>(gC, out, 1.0f / (float)rows);
}